// Round 16
// baseline (25.937 us; speedup 1.0000x reference)
//
#include <hip/hip_runtime.h>
#include <math.h>

#define SD 39
#define BLOCK 512   // 8 waves/block; 4 blocks/CU (LDS 28.7KB) -> 32 waves/CU

typedef _Float16 half8 __attribute__((ext_vector_type(8)));
typedef float f32x4 __attribute__((ext_vector_type(4)));

// ---- d_ws layout (dword offsets). All weight data pre-packed into per-lane
// MFMA fragments: frag arrays are [nfrag][64 lanes] of half8/f32x4 (16B each).
// Slot k-assignments are chosen by US and baked into BOTH the weight frags
// (repack) and the data frags (main kernel); MFMA pairs A-slot(g,j) with
// B-slot(g,j), so any consistent choice works.
#define DW_AW1 0      // 8 frags  (mt0..3 x ks0..1)   k = ks*32 + 8g + j ; 0 if k>=39
#define DW_AB1 2048   // 4 frags  f32x4 bias: eb1[mt*16+4g+r]
#define DW_AW2 3072   // 4 frags  (mt0..1 x ks0..1)   o1 = ks*32+16*(j>>2)+4g+(j&3)
#define DW_AB2 4096   // 2 frags  eb2[mt*16+4g+r]
#define DW_AW3 4608   // 1 frag   m=c<4: ew3[c][o2], o2=16*(j>>2)+4g+(j&3); else 0
#define DW_AB3 4864   // 1 frag   g==0 ? eb3[r] : 0
#define DW_AD1 5120   // 2 frags  (g==0&&j<4) ? dw1[(mt*16+c)*4+j] : 0
#define DW_AE1 5632   // 2 frags  db1[mt*16+4g+r]
#define DW_AD2 6144   // 1 frag   dw2[c*32 + 16*(j>>2)+4g+(j&3)]
#define DW_AE2 6400   // 1 frag   db2[4g+r]
#define DW_AD3 6656   // 1 frag   (c<8&&j<4) ? dw3[c*16+4g+j] : 0
#define DW_AE3 6912   // 1 frag   (4g+r<8) ? db3[4g+r] : 0
#define DW_QPE 7168   // qp[0,2,4,6]
#define DW_TOT 7172   // dwords (28688 B) -> staged to LDS per block

__global__ void repack_kernel(
    const float* __restrict__ ew1, const float* __restrict__ eb1,
    const float* __restrict__ ew2, const float* __restrict__ eb2,
    const float* __restrict__ ew3, const float* __restrict__ eb3,
    const float* __restrict__ qp,
    const float* __restrict__ dw1, const float* __restrict__ db1,
    const float* __restrict__ dw2, const float* __restrict__ db2,
    const float* __restrict__ dw3, const float* __restrict__ db3,
    float* __restrict__ ws)
{
    _Float16* wh = (_Float16*)ws;
    const int t0 = threadIdx.x + blockIdx.x * blockDim.x;
    const int stride = blockDim.x * gridDim.x;

    for (int i = t0; i < 8 * 512; i += stride) {          // AW1
        int frag = i >> 9, lane = (i >> 3) & 63, j = i & 7;
        int mt = frag >> 1, ks = frag & 1, g = lane >> 4, c = lane & 15;
        int m = mt * 16 + c, k = ks * 32 + 8 * g + j;
        wh[DW_AW1 * 2 + i] = (k < SD) ? (_Float16)ew1[m * SD + k] : (_Float16)0.0f;
    }
    for (int i = t0; i < 4 * 512; i += stride) {          // AW2
        int frag = i >> 9, lane = (i >> 3) & 63, j = i & 7;
        int mt = frag >> 1, ks = frag & 1, g = lane >> 4, c = lane & 15;
        int m = mt * 16 + c, o1 = ks * 32 + 16 * (j >> 2) + 4 * g + (j & 3);
        wh[DW_AW2 * 2 + i] = (_Float16)ew2[m * 64 + o1];
    }
    for (int i = t0; i < 512; i += stride) {              // AW3
        int lane = (i >> 3) & 63, j = i & 7, g = lane >> 4, c = lane & 15;
        int o2 = 16 * (j >> 2) + 4 * g + (j & 3);
        wh[DW_AW3 * 2 + i] = (c < 4) ? (_Float16)ew3[c * 32 + o2] : (_Float16)0.0f;
    }
    for (int i = t0; i < 2 * 512; i += stride) {          // AD1
        int frag = i >> 9, lane = (i >> 3) & 63, j = i & 7;
        int g = lane >> 4, c = lane & 15, m = frag * 16 + c;
        wh[DW_AD1 * 2 + i] = (g == 0 && j < 4) ? (_Float16)dw1[m * 4 + j] : (_Float16)0.0f;
    }
    for (int i = t0; i < 512; i += stride) {              // AD2
        int lane = (i >> 3) & 63, j = i & 7, g = lane >> 4, c = lane & 15;
        int k1 = 16 * (j >> 2) + 4 * g + (j & 3);
        wh[DW_AD2 * 2 + i] = (_Float16)dw2[c * 32 + k1];
    }
    for (int i = t0; i < 512; i += stride) {              // AD3
        int lane = (i >> 3) & 63, j = i & 7, g = lane >> 4, c = lane & 15;
        wh[DW_AD3 * 2 + i] = (c < 8 && j < 4) ? (_Float16)dw3[c * 16 + 4 * g + j]
                                              : (_Float16)0.0f;
    }
    for (int i = t0; i < 1024; i += stride) {             // AB1
        int mt = i >> 8, lane = (i >> 2) & 63, r = i & 3, g = lane >> 4;
        ws[DW_AB1 + i] = eb1[mt * 16 + 4 * g + r];
    }
    for (int i = t0; i < 512; i += stride) {              // AB2
        int mt = i >> 8, lane = (i >> 2) & 63, r = i & 3, g = lane >> 4;
        ws[DW_AB2 + i] = eb2[mt * 16 + 4 * g + r];
    }
    for (int i = t0; i < 256; i += stride) {              // AB3
        int lane = (i >> 2) & 63, r = i & 3, g = lane >> 4;
        ws[DW_AB3 + i] = (g == 0) ? eb3[r] : 0.0f;
    }
    for (int i = t0; i < 512; i += stride) {              // AE1
        int mt = i >> 8, lane = (i >> 2) & 63, r = i & 3, g = lane >> 4;
        ws[DW_AE1 + i] = db1[mt * 16 + 4 * g + r];
    }
    for (int i = t0; i < 256; i += stride) {              // AE2
        int lane = (i >> 2) & 63, r = i & 3, g = lane >> 4;
        ws[DW_AE2 + i] = db2[4 * g + r];
    }
    for (int i = t0; i < 256; i += stride) {              // AE3
        int lane = (i >> 2) & 63, r = i & 3, g = lane >> 4;
        ws[DW_AE3 + i] = (4 * g + r < 8) ? db3[4 * g + r] : 0.0f;
    }
    for (int i = t0; i < 4; i += stride) ws[DW_QPE + i] = qp[2 * i];
}

__global__ __launch_bounds__(BLOCK)
void qnet_kernel(const float* __restrict__ state,
                 const float* __restrict__ wsf,
                 float* __restrict__ out,
                 int ntiles, int nwaves)
{
    // Weights staged once per block; per-tile frag reads ride the LDS pipe
    // (lane-linear ds_read_b128, conflict-free), keeping L1 for state.
    __shared__ __align__(16) float lf[DW_TOT];
    {
        const float4* src4 = (const float4*)wsf;
        float4* dst4 = (float4*)lf;
        for (int i = threadIdx.x; i < DW_TOT / 4; i += BLOCK) dst4[i] = src4[i];
    }
    __syncthreads();

    const int lane = threadIdx.x & 63;
    const int g = lane >> 4, c = lane & 15;
    const int wv = threadIdx.x >> 6;                 // 0..7
    const int gwave = blockIdx.x * (BLOCK / 64) + wv;

    const half8* hws = (const half8*)lf;
    const f32x4* fws = (const f32x4*)lf;
    const float* qpep = lf + DW_QPE;

    // 2 adjacent tiles per wave (rows 32*gwave .. 32*gwave+31): L1/L2-local.
    for (int tile = 2 * gwave; tile < 2 * gwave + 2 && tile < ntiles; tile++) {
        const long long R = (long long)tile * 16;
        const float* sp = state + (R + c) * SD;

        // ---- state B-fragments. ks0: col 8g+j (all live). ks1: col 32+8g+j
        //      -> weights zero for g>=1, only g==0 lanes load cols 32..38. ----
        float4 s0 = *(const float4*)(sp + 8 * g);
        float4 s1 = *(const float4*)(sp + 8 * g + 4);
        float4 s2 = make_float4(0.f, 0.f, 0.f, 0.f);
        float4 s3 = make_float4(0.f, 0.f, 0.f, 0.f);
        if (g == 0) {
            s2 = *(const float4*)(sp + 32);   // cols 32..35
            s3 = *(const float4*)(sp + 35);   // cols 35..38 (in-bounds)
        }
        half8 x0, x1;
        x0[0] = (_Float16)s0.x; x0[1] = (_Float16)s0.y;
        x0[2] = (_Float16)s0.z; x0[3] = (_Float16)s0.w;
        x0[4] = (_Float16)s1.x; x0[5] = (_Float16)s1.y;
        x0[6] = (_Float16)s1.z; x0[7] = (_Float16)s1.w;
        x1[0] = (_Float16)s2.x; x1[1] = (_Float16)s2.y;
        x1[2] = (_Float16)s2.z; x1[3] = (_Float16)s2.w;
        x1[4] = (_Float16)s3.y; x1[5] = (_Float16)s3.z;
        x1[6] = (_Float16)s3.w; x1[7] = (_Float16)0.0f;

        // ---- L1: C1^T[o1][batch], 4 M-tiles x 2 K-steps ----
        f32x4 c1[4];
        #pragma unroll
        for (int mt = 0; mt < 4; mt++) {
            f32x4 acc = fws[DW_AB1 / 4 + mt * 64 + lane];
            acc = __builtin_amdgcn_mfma_f32_16x16x32_f16(
                      hws[DW_AW1 / 4 + (mt * 2 + 0) * 64 + lane], x0, acc, 0, 0, 0);
            acc = __builtin_amdgcn_mfma_f32_16x16x32_f16(
                      hws[DW_AW1 / 4 + (mt * 2 + 1) * 64 + lane], x1, acc, 0, 0, 0);
            c1[mt] = acc;
        }
        half8 hb0, hb1;
        #pragma unroll
        for (int j = 0; j < 8; j++) {
            hb0[j] = (_Float16)fmaxf(c1[j >> 2][j & 3], 0.0f);
            hb1[j] = (_Float16)fmaxf(c1[2 + (j >> 2)][j & 3], 0.0f);
        }

        // ---- L2: 2 M-tiles x 2 K-steps ----
        f32x4 c2[2];
        #pragma unroll
        for (int mt = 0; mt < 2; mt++) {
            f32x4 acc = fws[DW_AB2 / 4 + mt * 64 + lane];
            acc = __builtin_amdgcn_mfma_f32_16x16x32_f16(
                      hws[DW_AW2 / 4 + (mt * 2 + 0) * 64 + lane], hb0, acc, 0, 0, 0);
            acc = __builtin_amdgcn_mfma_f32_16x16x32_f16(
                      hws[DW_AW2 / 4 + (mt * 2 + 1) * 64 + lane], hb1, acc, 0, 0, 0);
            c2[mt] = acc;
        }
        half8 hb2;
        #pragma unroll
        for (int j = 0; j < 8; j++)
            hb2[j] = (_Float16)fmaxf(c2[j >> 2][j & 3], 0.0f);

        // ---- L3: enc^T (rows valid only in g==0 lanes; rest zeroed by wts) ----
        f32x4 e = __builtin_amdgcn_mfma_f32_16x16x32_f16(
                      hws[DW_AW3 / 4 + lane], hb2, fws[DW_AB3 / 4 + lane], 0, 0, 0);

        // ---- quantum: ev_i = prod_{j<=i} cos(tanh(e_j)*pi + qp[2j]) ----
        // (RZ cancels under Z-measure; CNOT chain -> bit i = b0^..^bi)
        float ev[4]; float cp = 1.0f;
        #pragma unroll
        for (int r = 0; r < 4; r++) {
            float ex = __expf(2.0f * e[r]);              // tanh = 1 - 2/(e^2x+1)
            float enc = 1.0f - 2.0f / (ex + 1.0f);
            float th = fmaf(enc, 3.14159265358979323846f, qpep[r]);
            cp *= __cosf(th);
            ev[r] = cp;
        }
        half8 evb;
        evb[0] = (_Float16)ev[0]; evb[1] = (_Float16)ev[1];
        evb[2] = (_Float16)ev[2]; evb[3] = (_Float16)ev[3];
        evb[4] = (_Float16)0.0f;  evb[5] = (_Float16)0.0f;
        evb[6] = (_Float16)0.0f;  evb[7] = (_Float16)0.0f;

        // ---- D1: 2 M-tiles, K=4(pad32) ----
        f32x4 d1c[2];
        #pragma unroll
        for (int mt = 0; mt < 2; mt++)
            d1c[mt] = __builtin_amdgcn_mfma_f32_16x16x32_f16(
                          hws[DW_AD1 / 4 + mt * 64 + lane], evb,
                          fws[DW_AE1 / 4 + mt * 64 + lane], 0, 0, 0);
        half8 db;
        #pragma unroll
        for (int j = 0; j < 8; j++)
            db[j] = (_Float16)fmaxf(d1c[j >> 2][j & 3], 0.0f);

        // ---- D2: K=32 ----
        f32x4 d2c = __builtin_amdgcn_mfma_f32_16x16x32_f16(
                        hws[DW_AD2 / 4 + lane], db, fws[DW_AE2 / 4 + lane], 0, 0, 0);
        half8 d2b;
        d2b[0] = (_Float16)fmaxf(d2c[0], 0.0f);
        d2b[1] = (_Float16)fmaxf(d2c[1], 0.0f);
        d2b[2] = (_Float16)fmaxf(d2c[2], 0.0f);
        d2b[3] = (_Float16)fmaxf(d2c[3], 0.0f);
        d2b[4] = (_Float16)0.0f; d2b[5] = (_Float16)0.0f;
        d2b[6] = (_Float16)0.0f; d2b[7] = (_Float16)0.0f;

        // ---- D3: K=16(pad32); out rows 0..7: g=0 -> dims 0-3, g=1 -> 4-7 ----
        f32x4 o = __builtin_amdgcn_mfma_f32_16x16x32_f16(
                      hws[DW_AD3 / 4 + lane], d2b, fws[DW_AE3 / 4 + lane], 0, 0, 0);

        if (lane < 32) {
            float4* op = (float4*)(out + (R + c) * 8 + 4 * g);
            *op = make_float4(o[0], o[1], o[2], o[3]);
        }
    }
}

extern "C" void kernel_launch(void* const* d_in, const int* in_sizes, int n_in,
                              void* d_out, int out_size, void* d_ws, size_t ws_size,
                              hipStream_t stream) {
    const float* state = (const float*)d_in[0];
    const float* ew1 = (const float*)d_in[1];
    const float* eb1 = (const float*)d_in[2];
    const float* ew2 = (const float*)d_in[3];
    const float* eb2 = (const float*)d_in[4];
    const float* ew3 = (const float*)d_in[5];
    const float* eb3 = (const float*)d_in[6];
    const float* qp  = (const float*)d_in[7];
    const float* dw1 = (const float*)d_in[8];
    const float* db1 = (const float*)d_in[9];
    const float* dw2 = (const float*)d_in[10];
    const float* db2 = (const float*)d_in[11];
    const float* dw3 = (const float*)d_in[12];
    const float* db3 = (const float*)d_in[13];
    float* out = (float*)d_out;
    float* ws  = (float*)d_ws;

    const int B = in_sizes[0] / SD;
    const int ntiles = B / 16;                    // 262144 -> 16384

    hipLaunchKernelGGL(repack_kernel, dim3(16), dim3(256), 0, stream,
                       ew1, eb1, ew2, eb2, ew3, eb3, qp,
                       dw1, db1, dw2, db2, dw3, db3, ws);

    // 1024 blocks x 8 waves = 8192 waves, 2 tiles/wave;
    // 4 blocks/CU (LDS+thread caps) -> 32 waves/CU = 8/SIMD (was 4/SIMD).
    const int blocks = 1024;
    const int nwaves = blocks * (BLOCK / 64);
    hipLaunchKernelGGL(qnet_kernel, dim3(blocks), dim3(BLOCK), 0, stream,
                       state, ws, out, ntiles, nwaves);
}

// Round 17
// 24.218 us; speedup vs baseline: 1.0710x; 1.0710x over previous
//
#include <hip/hip_runtime.h>
#include <math.h>

#define SD 39
#define BLOCK 256

typedef _Float16 half8 __attribute__((ext_vector_type(8)));
typedef float f32x4 __attribute__((ext_vector_type(4)));

// ---- d_ws layout (dword offsets); per-lane MFMA fragments, see R14/R15 ----
#define DW_AW1 0      // 8 frags  (mt0..3 x ks0..1)   k = ks*32 + 8g + j ; 0 if k>=39
#define DW_AB1 2048   // 4 frags  f32x4 bias: eb1[mt*16+4g+r]
#define DW_AW2 3072   // 4 frags  (mt0..1 x ks0..1)   o1 = ks*32+16*(j>>2)+4g+(j&3)
#define DW_AB2 4096   // 2 frags  eb2[mt*16+4g+r]
#define DW_AW3 4608   // 1 frag   c<4: ew3[c][o2], o2=16*(j>>2)+4g+(j&3); else 0
#define DW_AB3 4864   // 1 frag   g==0 ? eb3[r] : 0
#define DW_AD1 5120   // 2 frags  (g==0&&j<4) ? dw1[(mt*16+c)*4+j] : 0
#define DW_AE1 5632   // 2 frags  db1[mt*16+4g+r]
#define DW_AD2 6144   // 1 frag   dw2[c*32 + 16*(j>>2)+4g+(j&3)]
#define DW_AE2 6400   // 1 frag   db2[4g+r]
#define DW_AD3 6656   // 1 frag   (c<8&&j<4) ? dw3[c*16+4g+j] : 0
#define DW_AE3 6912   // 1 frag   (4g+r<8) ? db3[4g+r] : 0
#define DW_QPE 7168   // qp[0,2,4,6]
#define DW_TOT 7172   // dwords (28688 B) -> staged to LDS per block

__global__ void repack_kernel(
    const float* __restrict__ ew1, const float* __restrict__ eb1,
    const float* __restrict__ ew2, const float* __restrict__ eb2,
    const float* __restrict__ ew3, const float* __restrict__ eb3,
    const float* __restrict__ qp,
    const float* __restrict__ dw1, const float* __restrict__ db1,
    const float* __restrict__ dw2, const float* __restrict__ db2,
    const float* __restrict__ dw3, const float* __restrict__ db3,
    float* __restrict__ ws)
{
    _Float16* wh = (_Float16*)ws;
    const int t0 = threadIdx.x + blockIdx.x * blockDim.x;
    const int stride = blockDim.x * gridDim.x;

    for (int i = t0; i < 8 * 512; i += stride) {          // AW1
        int frag = i >> 9, lane = (i >> 3) & 63, j = i & 7;
        int mt = frag >> 1, ks = frag & 1, g = lane >> 4, c = lane & 15;
        int m = mt * 16 + c, k = ks * 32 + 8 * g + j;
        wh[DW_AW1 * 2 + i] = (k < SD) ? (_Float16)ew1[m * SD + k] : (_Float16)0.0f;
    }
    for (int i = t0; i < 4 * 512; i += stride) {          // AW2
        int frag = i >> 9, lane = (i >> 3) & 63, j = i & 7;
        int mt = frag >> 1, ks = frag & 1, g = lane >> 4, c = lane & 15;
        int m = mt * 16 + c, o1 = ks * 32 + 16 * (j >> 2) + 4 * g + (j & 3);
        wh[DW_AW2 * 2 + i] = (_Float16)ew2[m * 64 + o1];
    }
    for (int i = t0; i < 512; i += stride) {              // AW3
        int lane = (i >> 3) & 63, j = i & 7, g = lane >> 4, c = lane & 15;
        int o2 = 16 * (j >> 2) + 4 * g + (j & 3);
        wh[DW_AW3 * 2 + i] = (c < 4) ? (_Float16)ew3[c * 32 + o2] : (_Float16)0.0f;
    }
    for (int i = t0; i < 2 * 512; i += stride) {          // AD1
        int frag = i >> 9, lane = (i >> 3) & 63, j = i & 7;
        int g = lane >> 4, c = lane & 15, m = frag * 16 + c;
        wh[DW_AD1 * 2 + i] = (g == 0 && j < 4) ? (_Float16)dw1[m * 4 + j] : (_Float16)0.0f;
    }
    for (int i = t0; i < 512; i += stride) {              // AD2
        int lane = (i >> 3) & 63, j = i & 7, g = lane >> 4, c = lane & 15;
        int k1 = 16 * (j >> 2) + 4 * g + (j & 3);
        wh[DW_AD2 * 2 + i] = (_Float16)dw2[c * 32 + k1];
    }
    for (int i = t0; i < 512; i += stride) {              // AD3
        int lane = (i >> 3) & 63, j = i & 7, g = lane >> 4, c = lane & 15;
        wh[DW_AD3 * 2 + i] = (c < 8 && j < 4) ? (_Float16)dw3[c * 16 + 4 * g + j]
                                              : (_Float16)0.0f;
    }
    for (int i = t0; i < 1024; i += stride) {             // AB1
        int mt = i >> 8, lane = (i >> 2) & 63, r = i & 3, g = lane >> 4;
        ws[DW_AB1 + i] = eb1[mt * 16 + 4 * g + r];
    }
    for (int i = t0; i < 512; i += stride) {              // AB2
        int mt = i >> 8, lane = (i >> 2) & 63, r = i & 3, g = lane >> 4;
        ws[DW_AB2 + i] = eb2[mt * 16 + 4 * g + r];
    }
    for (int i = t0; i < 256; i += stride) {              // AB3
        int lane = (i >> 2) & 63, r = i & 3, g = lane >> 4;
        ws[DW_AB3 + i] = (g == 0) ? eb3[r] : 0.0f;
    }
    for (int i = t0; i < 512; i += stride) {              // AE1
        int mt = i >> 8, lane = (i >> 2) & 63, r = i & 3, g = lane >> 4;
        ws[DW_AE1 + i] = db1[mt * 16 + 4 * g + r];
    }
    for (int i = t0; i < 256; i += stride) {              // AE2
        int lane = (i >> 2) & 63, r = i & 3, g = lane >> 4;
        ws[DW_AE2 + i] = db2[4 * g + r];
    }
    for (int i = t0; i < 256; i += stride) {              // AE3
        int lane = (i >> 2) & 63, r = i & 3, g = lane >> 4;
        ws[DW_AE3 + i] = (4 * g + r < 8) ? db3[4 * g + r] : 0.0f;
    }
    for (int i = t0; i < 4; i += stride) ws[DW_QPE + i] = qp[2 * i];
}

// Load one tile's state B-fragments (rows R..R+15, lane c owns row R+c).
#define LOAD_STATE(R, X0, X1)                                              \
    {                                                                      \
        const float* sp = state + ((R) + c) * SD;                          \
        float4 s0 = *(const float4*)(sp + 8 * g);                          \
        float4 s1 = *(const float4*)(sp + 8 * g + 4);                      \
        float4 s2 = make_float4(0.f, 0.f, 0.f, 0.f);                       \
        float4 s3 = make_float4(0.f, 0.f, 0.f, 0.f);                       \
        if (g == 0) {                                                      \
            s2 = *(const float4*)(sp + 32);                                \
            s3 = *(const float4*)(sp + 35);                                \
        }                                                                  \
        X0[0] = (_Float16)s0.x; X0[1] = (_Float16)s0.y;                    \
        X0[2] = (_Float16)s0.z; X0[3] = (_Float16)s0.w;                    \
        X0[4] = (_Float16)s1.x; X0[5] = (_Float16)s1.y;                    \
        X0[6] = (_Float16)s1.z; X0[7] = (_Float16)s1.w;                    \
        X1[0] = (_Float16)s2.x; X1[1] = (_Float16)s2.y;                    \
        X1[2] = (_Float16)s2.z; X1[3] = (_Float16)s2.w;                    \
        X1[4] = (_Float16)s3.y; X1[5] = (_Float16)s3.z;                    \
        X1[6] = (_Float16)s3.w; X1[7] = (_Float16)0.0f;                    \
    }

__global__ __launch_bounds__(BLOCK)
void qnet_kernel(const float* __restrict__ state,
                 const float* __restrict__ wsf,
                 float* __restrict__ out,
                 int ntiles, int nwaves)
{
    __shared__ __align__(16) float lf[DW_TOT];
    {
        const float4* src4 = (const float4*)wsf;
        float4* dst4 = (float4*)lf;
        for (int i = threadIdx.x; i < DW_TOT / 4; i += BLOCK) dst4[i] = src4[i];
    }
    __syncthreads();

    const int lane = threadIdx.x & 63;
    const int g = lane >> 4, c = lane & 15;
    const int gwave = blockIdx.x * (BLOCK / 64) + (threadIdx.x >> 6);

    const half8* hws = (const half8*)lf;
    const f32x4* fws = (const f32x4*)lf;
    const float* qpep = lf + DW_QPE;

    // PAIRED TILES: two independent chains per iteration. Each weight-frag
    // ds_read feeds BOTH tiles' MFMAs (halves LDS traffic), and the two
    // dependency chains hide each other's ds_read/MFMA/transcendental
    // latency -- ILP substitutes for the VGPR-capped (4 waves/SIMD)
    // occupancy that R16 showed we cannot raise.
    for (int p = 2 * gwave; p < 2 * gwave + 2 && 2 * p + 1 < ntiles; p++) {
        const long long RA = (long long)(2 * p) * 16;
        const long long RB = RA + 16;

        half8 x0a, x1a, x0b, x1b;
        LOAD_STATE(RA, x0a, x1a)
        LOAD_STATE(RB, x0b, x1b)

        // ---- L1: 4 M-tiles x 2 K-steps, both tiles per frag ----
        f32x4 c1a[4], c1b[4];
        #pragma unroll
        for (int mt = 0; mt < 4; mt++) {
            half8 w0 = hws[DW_AW1 / 4 + (mt * 2 + 0) * 64 + lane];
            half8 w1 = hws[DW_AW1 / 4 + (mt * 2 + 1) * 64 + lane];
            f32x4 bias = fws[DW_AB1 / 4 + mt * 64 + lane];
            f32x4 ta = __builtin_amdgcn_mfma_f32_16x16x32_f16(w0, x0a, bias, 0, 0, 0);
            f32x4 tb = __builtin_amdgcn_mfma_f32_16x16x32_f16(w0, x0b, bias, 0, 0, 0);
            c1a[mt] = __builtin_amdgcn_mfma_f32_16x16x32_f16(w1, x1a, ta, 0, 0, 0);
            c1b[mt] = __builtin_amdgcn_mfma_f32_16x16x32_f16(w1, x1b, tb, 0, 0, 0);
        }
        half8 hb0a, hb1a, hb0b, hb1b;
        #pragma unroll
        for (int j = 0; j < 8; j++) {
            hb0a[j] = (_Float16)fmaxf(c1a[j >> 2][j & 3], 0.0f);
            hb1a[j] = (_Float16)fmaxf(c1a[2 + (j >> 2)][j & 3], 0.0f);
            hb0b[j] = (_Float16)fmaxf(c1b[j >> 2][j & 3], 0.0f);
            hb1b[j] = (_Float16)fmaxf(c1b[2 + (j >> 2)][j & 3], 0.0f);
        }

        // ---- L2: 2 M-tiles x 2 K-steps ----
        f32x4 c2a[2], c2b[2];
        #pragma unroll
        for (int mt = 0; mt < 2; mt++) {
            half8 w0 = hws[DW_AW2 / 4 + (mt * 2 + 0) * 64 + lane];
            half8 w1 = hws[DW_AW2 / 4 + (mt * 2 + 1) * 64 + lane];
            f32x4 bias = fws[DW_AB2 / 4 + mt * 64 + lane];
            f32x4 ta = __builtin_amdgcn_mfma_f32_16x16x32_f16(w0, hb0a, bias, 0, 0, 0);
            f32x4 tb = __builtin_amdgcn_mfma_f32_16x16x32_f16(w0, hb0b, bias, 0, 0, 0);
            c2a[mt] = __builtin_amdgcn_mfma_f32_16x16x32_f16(w1, hb1a, ta, 0, 0, 0);
            c2b[mt] = __builtin_amdgcn_mfma_f32_16x16x32_f16(w1, hb1b, tb, 0, 0, 0);
        }
        half8 hb2a, hb2b;
        #pragma unroll
        for (int j = 0; j < 8; j++) {
            hb2a[j] = (_Float16)fmaxf(c2a[j >> 2][j & 3], 0.0f);
            hb2b[j] = (_Float16)fmaxf(c2b[j >> 2][j & 3], 0.0f);
        }

        // ---- L3 ----
        {
            half8 w = hws[DW_AW3 / 4 + lane];
            f32x4 bias = fws[DW_AB3 / 4 + lane];
            f32x4 ea = __builtin_amdgcn_mfma_f32_16x16x32_f16(w, hb2a, bias, 0, 0, 0);
            f32x4 eb = __builtin_amdgcn_mfma_f32_16x16x32_f16(w, hb2b, bias, 0, 0, 0);

            // ---- quantum, both tiles interleaved ----
            float eva[4], evb4[4]; float cpa = 1.0f, cpb = 1.0f;
            #pragma unroll
            for (int r = 0; r < 4; r++) {
                float exa = __expf(2.0f * ea[r]);
                float exb = __expf(2.0f * eb[r]);
                float ta = 1.0f - 2.0f / (exa + 1.0f);
                float tb = 1.0f - 2.0f / (exb + 1.0f);
                float qpe = qpep[r];
                cpa *= __cosf(fmaf(ta, 3.14159265358979323846f, qpe));
                cpb *= __cosf(fmaf(tb, 3.14159265358979323846f, qpe));
                eva[r] = cpa; evb4[r] = cpb;
            }
            half8 evfa, evfb;
            #pragma unroll
            for (int j = 0; j < 8; j++) {
                evfa[j] = (j < 4) ? (_Float16)eva[j] : (_Float16)0.0f;
                evfb[j] = (j < 4) ? (_Float16)evb4[j] : (_Float16)0.0f;
            }

            // ---- D1: 2 M-tiles ----
            f32x4 d1a[2], d1b[2];
            #pragma unroll
            for (int mt = 0; mt < 2; mt++) {
                half8 wd = hws[DW_AD1 / 4 + mt * 64 + lane];
                f32x4 be = fws[DW_AE1 / 4 + mt * 64 + lane];
                d1a[mt] = __builtin_amdgcn_mfma_f32_16x16x32_f16(wd, evfa, be, 0, 0, 0);
                d1b[mt] = __builtin_amdgcn_mfma_f32_16x16x32_f16(wd, evfb, be, 0, 0, 0);
            }
            half8 dba, dbb;
            #pragma unroll
            for (int j = 0; j < 8; j++) {
                dba[j] = (_Float16)fmaxf(d1a[j >> 2][j & 3], 0.0f);
                dbb[j] = (_Float16)fmaxf(d1b[j >> 2][j & 3], 0.0f);
            }

            // ---- D2 ----
            half8 wd2 = hws[DW_AD2 / 4 + lane];
            f32x4 be2 = fws[DW_AE2 / 4 + lane];
            f32x4 d2a = __builtin_amdgcn_mfma_f32_16x16x32_f16(wd2, dba, be2, 0, 0, 0);
            f32x4 d2b = __builtin_amdgcn_mfma_f32_16x16x32_f16(wd2, dbb, be2, 0, 0, 0);
            half8 d2fa, d2fb;
            #pragma unroll
            for (int j = 0; j < 8; j++) {
                d2fa[j] = (j < 4) ? (_Float16)fmaxf(d2a[j], 0.0f) : (_Float16)0.0f;
                d2fb[j] = (j < 4) ? (_Float16)fmaxf(d2b[j], 0.0f) : (_Float16)0.0f;
            }

            // ---- D3 + stores ----
            half8 wd3 = hws[DW_AD3 / 4 + lane];
            f32x4 be3 = fws[DW_AE3 / 4 + lane];
            f32x4 oa = __builtin_amdgcn_mfma_f32_16x16x32_f16(wd3, d2fa, be3, 0, 0, 0);
            f32x4 ob = __builtin_amdgcn_mfma_f32_16x16x32_f16(wd3, d2fb, be3, 0, 0, 0);

            if (lane < 32) {
                float4* opa = (float4*)(out + (RA + c) * 8 + 4 * g);
                *opa = make_float4(oa[0], oa[1], oa[2], oa[3]);
                float4* opb = (float4*)(out + (RB + c) * 8 + 4 * g);
                *opb = make_float4(ob[0], ob[1], ob[2], ob[3]);
            }
        }
    }
}

extern "C" void kernel_launch(void* const* d_in, const int* in_sizes, int n_in,
                              void* d_out, int out_size, void* d_ws, size_t ws_size,
                              hipStream_t stream) {
    const float* state = (const float*)d_in[0];
    const float* ew1 = (const float*)d_in[1];
    const float* eb1 = (const float*)d_in[2];
    const float* ew2 = (const float*)d_in[3];
    const float* eb2 = (const float*)d_in[4];
    const float* ew3 = (const float*)d_in[5];
    const float* eb3 = (const float*)d_in[6];
    const float* qp  = (const float*)d_in[7];
    const float* dw1 = (const float*)d_in[8];
    const float* db1 = (const float*)d_in[9];
    const float* dw2 = (const float*)d_in[10];
    const float* db2 = (const float*)d_in[11];
    const float* dw3 = (const float*)d_in[12];
    const float* db3 = (const float*)d_in[13];
    float* out = (float*)d_out;
    float* ws  = (float*)d_ws;

    const int B = in_sizes[0] / SD;
    const int ntiles = B / 16;                    // 262144 -> 16384

    hipLaunchKernelGGL(repack_kernel, dim3(16), dim3(256), 0, stream,
                       ew1, eb1, ew2, eb2, ew3, eb3, qp,
                       dw1, db1, dw2, db2, dw3, db3, ws);

    // 1024 blocks x 4 waves = 4096 waves; 2 tile-PAIRS (4 tiles) per wave.
    const int blocks = 1024;
    const int nwaves = blocks * (BLOCK / 64);
    hipLaunchKernelGGL(qnet_kernel, dim3(blocks), dim3(BLOCK), 0, stream,
                       state, ws, out, ntiles, nwaves);
}

// Round 18
// 23.783 us; speedup vs baseline: 1.0906x; 1.0183x over previous
//
#include <hip/hip_runtime.h>
#include <math.h>

#define SD 39
#define BLOCK 256

typedef _Float16 half8 __attribute__((ext_vector_type(8)));
typedef float f32x4 __attribute__((ext_vector_type(4)));

// ---- LDS layout (dword offsets); per-lane MFMA fragments, see R14/R15.
// Each block builds this image directly from the raw weight arrays (the
// former repack kernel is now inlined -- one kernel, no d_ws, no serialized
// launch). Frag arrays: [nfrag][64 lanes] of half8/f32x4 (16B each). Slot
// k-assignments are OUR choice, baked consistently into weight frags here
// and data frags in the main loop; MFMA pairs A-slot(g,j) with B-slot(g,j).
#define DW_AW1 0      // 8 frags  (mt0..3 x ks0..1)   k = ks*32 + 8g + j ; 0 if k>=39
#define DW_AB1 2048   // 4 frags  f32x4 bias: eb1[mt*16+4g+r]
#define DW_AW2 3072   // 4 frags  (mt0..1 x ks0..1)   o1 = ks*32+16*(j>>2)+4g+(j&3)
#define DW_AB2 4096   // 2 frags  eb2[mt*16+4g+r]
#define DW_AW3 4608   // 1 frag   c<4: ew3[c][o2], o2=16*(j>>2)+4g+(j&3); else 0
#define DW_AB3 4864   // 1 frag   g==0 ? eb3[r] : 0
#define DW_AD1 5120   // 2 frags  (g==0&&j<4) ? dw1[(mt*16+c)*4+j] : 0
#define DW_AE1 5632   // 2 frags  db1[mt*16+4g+r]
#define DW_AD2 6144   // 1 frag   dw2[c*32 + 16*(j>>2)+4g+(j&3)]
#define DW_AE2 6400   // 1 frag   db2[4g+r]
#define DW_AD3 6656   // 1 frag   (c<8&&j<4) ? dw3[c*16+4g+j] : 0
#define DW_AE3 6912   // 1 frag   (4g+r<8) ? db3[4g+r] : 0
#define DW_QPE 7168   // qp[0,2,4,6]
#define DW_TOT 7172   // dwords = 28688 B LDS

// Load one tile's state B-fragments (rows R..R+15, lane c owns row R+c).
#define LOAD_STATE(R, X0, X1)                                              \
    {                                                                      \
        const float* sp = state + ((R) + c) * SD;                          \
        float4 s0 = *(const float4*)(sp + 8 * g);                          \
        float4 s1 = *(const float4*)(sp + 8 * g + 4);                      \
        float4 s2 = make_float4(0.f, 0.f, 0.f, 0.f);                       \
        float4 s3 = make_float4(0.f, 0.f, 0.f, 0.f);                       \
        if (g == 0) {                                                      \
            s2 = *(const float4*)(sp + 32);                                \
            s3 = *(const float4*)(sp + 35);                                \
        }                                                                  \
        X0[0] = (_Float16)s0.x; X0[1] = (_Float16)s0.y;                    \
        X0[2] = (_Float16)s0.z; X0[3] = (_Float16)s0.w;                    \
        X0[4] = (_Float16)s1.x; X0[5] = (_Float16)s1.y;                    \
        X0[6] = (_Float16)s1.z; X0[7] = (_Float16)s1.w;                    \
        X1[0] = (_Float16)s2.x; X1[1] = (_Float16)s2.y;                    \
        X1[2] = (_Float16)s2.z; X1[3] = (_Float16)s2.w;                    \
        X1[4] = (_Float16)s3.y; X1[5] = (_Float16)s3.z;                    \
        X1[6] = (_Float16)s3.w; X1[7] = (_Float16)0.0f;                    \
    }

__global__ __launch_bounds__(BLOCK)
__attribute__((amdgpu_waves_per_eu(4)))   // demand 4 waves/SIMD -> VGPR<=128
void qnet_kernel(const float* __restrict__ state,
                 const float* __restrict__ ew1, const float* __restrict__ eb1,
                 const float* __restrict__ ew2, const float* __restrict__ eb2,
                 const float* __restrict__ ew3, const float* __restrict__ eb3,
                 const float* __restrict__ qp,
                 const float* __restrict__ dw1, const float* __restrict__ db1,
                 const float* __restrict__ dw2, const float* __restrict__ db2,
                 const float* __restrict__ dw3, const float* __restrict__ db3,
                 float* __restrict__ out, int ntiles)
{
    __shared__ __align__(16) float lf[DW_TOT];
    _Float16* wh = (_Float16*)lf;
    const int tid = threadIdx.x;

    // ---- inline fragment repack (one-time per block; weights L2-resident) ----
    for (int i = tid; i < 8 * 512; i += BLOCK) {          // AW1
        int frag = i >> 9, lane = (i >> 3) & 63, j = i & 7;
        int mt = frag >> 1, ks = frag & 1, g = lane >> 4, c = lane & 15;
        int m = mt * 16 + c, k = ks * 32 + 8 * g + j;
        wh[DW_AW1 * 2 + i] = (k < SD) ? (_Float16)ew1[m * SD + k] : (_Float16)0.0f;
    }
    for (int i = tid; i < 4 * 512; i += BLOCK) {          // AW2
        int frag = i >> 9, lane = (i >> 3) & 63, j = i & 7;
        int mt = frag >> 1, ks = frag & 1, g = lane >> 4, c = lane & 15;
        int m = mt * 16 + c, o1 = ks * 32 + 16 * (j >> 2) + 4 * g + (j & 3);
        wh[DW_AW2 * 2 + i] = (_Float16)ew2[m * 64 + o1];
    }
    for (int i = tid; i < 512; i += BLOCK) {              // AW3
        int lane = (i >> 3) & 63, j = i & 7, g = lane >> 4, c = lane & 15;
        int o2 = 16 * (j >> 2) + 4 * g + (j & 3);
        wh[DW_AW3 * 2 + i] = (c < 4) ? (_Float16)ew3[c * 32 + o2] : (_Float16)0.0f;
    }
    for (int i = tid; i < 2 * 512; i += BLOCK) {          // AD1
        int frag = i >> 9, lane = (i >> 3) & 63, j = i & 7;
        int g = lane >> 4, c = lane & 15, m = frag * 16 + c;
        wh[DW_AD1 * 2 + i] = (g == 0 && j < 4) ? (_Float16)dw1[m * 4 + j]
                                               : (_Float16)0.0f;
    }
    for (int i = tid; i < 512; i += BLOCK) {              // AD2
        int lane = (i >> 3) & 63, j = i & 7, g = lane >> 4, c = lane & 15;
        int k1 = 16 * (j >> 2) + 4 * g + (j & 3);
        wh[DW_AD2 * 2 + i] = (_Float16)dw2[c * 32 + k1];
    }
    for (int i = tid; i < 512; i += BLOCK) {              // AD3
        int lane = (i >> 3) & 63, j = i & 7, g = lane >> 4, c = lane & 15;
        wh[DW_AD3 * 2 + i] = (c < 8 && j < 4) ? (_Float16)dw3[c * 16 + 4 * g + j]
                                              : (_Float16)0.0f;
    }
    for (int i = tid; i < 1024; i += BLOCK) {             // AB1
        int mt = i >> 8, lane = (i >> 2) & 63, r = i & 3, g = lane >> 4;
        lf[DW_AB1 + i] = eb1[mt * 16 + 4 * g + r];
    }
    for (int i = tid; i < 512; i += BLOCK) {              // AB2
        int mt = i >> 8, lane = (i >> 2) & 63, r = i & 3, g = lane >> 4;
        lf[DW_AB2 + i] = eb2[mt * 16 + 4 * g + r];
    }
    for (int i = tid; i < 256; i += BLOCK) {              // AB3
        int lane = (i >> 2) & 63, r = i & 3, g = lane >> 4;
        lf[DW_AB3 + i] = (g == 0) ? eb3[r] : 0.0f;
    }
    for (int i = tid; i < 512; i += BLOCK) {              // AE1
        int mt = i >> 8, lane = (i >> 2) & 63, r = i & 3, g = lane >> 4;
        lf[DW_AE1 + i] = db1[mt * 16 + 4 * g + r];
    }
    for (int i = tid; i < 256; i += BLOCK) {              // AE2
        int lane = (i >> 2) & 63, r = i & 3, g = lane >> 4;
        lf[DW_AE2 + i] = db2[4 * g + r];
    }
    for (int i = tid; i < 256; i += BLOCK) {              // AE3
        int lane = (i >> 2) & 63, r = i & 3, g = lane >> 4;
        lf[DW_AE3 + i] = (4 * g + r < 8) ? db3[4 * g + r] : 0.0f;
    }
    for (int i = tid; i < 4; i += BLOCK) lf[DW_QPE + i] = qp[2 * i];
    __syncthreads();

    const int lane = tid & 63;
    const int g = lane >> 4, c = lane & 15;
    const int gwave = blockIdx.x * (BLOCK / 64) + (tid >> 6);

    const half8* hws = (const half8*)lf;
    const f32x4* fws = (const f32x4*)lf;
    const float* qpep = lf + DW_QPE;

    // Paired tiles: each weight ds_read feeds both tiles' MFMAs; two
    // independent chains hide each other's latencies.
    for (int p = 2 * gwave; p < 2 * gwave + 2 && 2 * p + 1 < ntiles; p++) {
        const long long RA = (long long)(2 * p) * 16;
        const long long RB = RA + 16;

        half8 x0a, x1a, x0b, x1b;
        LOAD_STATE(RA, x0a, x1a)
        LOAD_STATE(RB, x0b, x1b)

        // ---- L1: 4 M-tiles x 2 K-steps ----
        f32x4 c1a[4], c1b[4];
        #pragma unroll
        for (int mt = 0; mt < 4; mt++) {
            half8 w0 = hws[DW_AW1 / 4 + (mt * 2 + 0) * 64 + lane];
            half8 w1 = hws[DW_AW1 / 4 + (mt * 2 + 1) * 64 + lane];
            f32x4 bias = fws[DW_AB1 / 4 + mt * 64 + lane];
            f32x4 ta = __builtin_amdgcn_mfma_f32_16x16x32_f16(w0, x0a, bias, 0, 0, 0);
            f32x4 tb = __builtin_amdgcn_mfma_f32_16x16x32_f16(w0, x0b, bias, 0, 0, 0);
            c1a[mt] = __builtin_amdgcn_mfma_f32_16x16x32_f16(w1, x1a, ta, 0, 0, 0);
            c1b[mt] = __builtin_amdgcn_mfma_f32_16x16x32_f16(w1, x1b, tb, 0, 0, 0);
        }
        half8 hb0a, hb1a, hb0b, hb1b;
        #pragma unroll
        for (int j = 0; j < 8; j++) {
            hb0a[j] = (_Float16)fmaxf(c1a[j >> 2][j & 3], 0.0f);
            hb1a[j] = (_Float16)fmaxf(c1a[2 + (j >> 2)][j & 3], 0.0f);
            hb0b[j] = (_Float16)fmaxf(c1b[j >> 2][j & 3], 0.0f);
            hb1b[j] = (_Float16)fmaxf(c1b[2 + (j >> 2)][j & 3], 0.0f);
        }

        // ---- L2: 2 M-tiles x 2 K-steps ----
        f32x4 c2a[2], c2b[2];
        #pragma unroll
        for (int mt = 0; mt < 2; mt++) {
            half8 w0 = hws[DW_AW2 / 4 + (mt * 2 + 0) * 64 + lane];
            half8 w1 = hws[DW_AW2 / 4 + (mt * 2 + 1) * 64 + lane];
            f32x4 bias = fws[DW_AB2 / 4 + mt * 64 + lane];
            f32x4 ta = __builtin_amdgcn_mfma_f32_16x16x32_f16(w0, hb0a, bias, 0, 0, 0);
            f32x4 tb = __builtin_amdgcn_mfma_f32_16x16x32_f16(w0, hb0b, bias, 0, 0, 0);
            c2a[mt] = __builtin_amdgcn_mfma_f32_16x16x32_f16(w1, hb1a, ta, 0, 0, 0);
            c2b[mt] = __builtin_amdgcn_mfma_f32_16x16x32_f16(w1, hb1b, tb, 0, 0, 0);
        }
        half8 hb2a, hb2b;
        #pragma unroll
        for (int j = 0; j < 8; j++) {
            hb2a[j] = (_Float16)fmaxf(c2a[j >> 2][j & 3], 0.0f);
            hb2b[j] = (_Float16)fmaxf(c2b[j >> 2][j & 3], 0.0f);
        }

        // ---- L3 ----
        half8 w3 = hws[DW_AW3 / 4 + lane];
        f32x4 b3 = fws[DW_AB3 / 4 + lane];
        f32x4 ea = __builtin_amdgcn_mfma_f32_16x16x32_f16(w3, hb2a, b3, 0, 0, 0);
        f32x4 eb = __builtin_amdgcn_mfma_f32_16x16x32_f16(w3, hb2b, b3, 0, 0, 0);

        // ---- quantum: ev_i = prod_{j<=i} cos(tanh(e_j)*pi + qp[2j]) ----
        // (RZ cancels under Z-measure; CNOT chain -> bit i = b0^..^bi)
        float eva[4], evb4[4]; float cpa = 1.0f, cpb = 1.0f;
        #pragma unroll
        for (int r = 0; r < 4; r++) {
            float exa = __expf(2.0f * ea[r]);
            float exb = __expf(2.0f * eb[r]);
            float ta = 1.0f - 2.0f / (exa + 1.0f);     // tanh(x)
            float tb = 1.0f - 2.0f / (exb + 1.0f);
            float qpe = qpep[r];
            cpa *= __cosf(fmaf(ta, 3.14159265358979323846f, qpe));
            cpb *= __cosf(fmaf(tb, 3.14159265358979323846f, qpe));
            eva[r] = cpa; evb4[r] = cpb;
        }
        half8 evfa, evfb;
        #pragma unroll
        for (int j = 0; j < 8; j++) {
            evfa[j] = (j < 4) ? (_Float16)eva[j] : (_Float16)0.0f;
            evfb[j] = (j < 4) ? (_Float16)evb4[j] : (_Float16)0.0f;
        }

        // ---- D1: 2 M-tiles ----
        f32x4 d1a[2], d1b[2];
        #pragma unroll
        for (int mt = 0; mt < 2; mt++) {
            half8 wd = hws[DW_AD1 / 4 + mt * 64 + lane];
            f32x4 be = fws[DW_AE1 / 4 + mt * 64 + lane];
            d1a[mt] = __builtin_amdgcn_mfma_f32_16x16x32_f16(wd, evfa, be, 0, 0, 0);
            d1b[mt] = __builtin_amdgcn_mfma_f32_16x16x32_f16(wd, evfb, be, 0, 0, 0);
        }
        half8 dba, dbb;
        #pragma unroll
        for (int j = 0; j < 8; j++) {
            dba[j] = (_Float16)fmaxf(d1a[j >> 2][j & 3], 0.0f);
            dbb[j] = (_Float16)fmaxf(d1b[j >> 2][j & 3], 0.0f);
        }

        // ---- D2 ----
        half8 wd2 = hws[DW_AD2 / 4 + lane];
        f32x4 be2 = fws[DW_AE2 / 4 + lane];
        f32x4 d2a = __builtin_amdgcn_mfma_f32_16x16x32_f16(wd2, dba, be2, 0, 0, 0);
        f32x4 d2b = __builtin_amdgcn_mfma_f32_16x16x32_f16(wd2, dbb, be2, 0, 0, 0);
        half8 d2fa, d2fb;
        #pragma unroll
        for (int j = 0; j < 8; j++) {
            d2fa[j] = (j < 4) ? (_Float16)fmaxf(d2a[j], 0.0f) : (_Float16)0.0f;
            d2fb[j] = (j < 4) ? (_Float16)fmaxf(d2b[j], 0.0f) : (_Float16)0.0f;
        }

        // ---- D3 + stores ----
        half8 wd3 = hws[DW_AD3 / 4 + lane];
        f32x4 be3 = fws[DW_AE3 / 4 + lane];
        f32x4 oa = __builtin_amdgcn_mfma_f32_16x16x32_f16(wd3, d2fa, be3, 0, 0, 0);
        f32x4 ob = __builtin_amdgcn_mfma_f32_16x16x32_f16(wd3, d2fb, be3, 0, 0, 0);

        if (lane < 32) {
            float4* opa = (float4*)(out + (RA + c) * 8 + 4 * g);
            *opa = make_float4(oa[0], oa[1], oa[2], oa[3]);
            float4* opb = (float4*)(out + (RB + c) * 8 + 4 * g);
            *opb = make_float4(ob[0], ob[1], ob[2], ob[3]);
        }
    }
}

extern "C" void kernel_launch(void* const* d_in, const int* in_sizes, int n_in,
                              void* d_out, int out_size, void* d_ws, size_t ws_size,
                              hipStream_t stream) {
    const float* state = (const float*)d_in[0];
    const float* ew1 = (const float*)d_in[1];
    const float* eb1 = (const float*)d_in[2];
    const float* ew2 = (const float*)d_in[3];
    const float* eb2 = (const float*)d_in[4];
    const float* ew3 = (const float*)d_in[5];
    const float* eb3 = (const float*)d_in[6];
    const float* qp  = (const float*)d_in[7];
    const float* dw1 = (const float*)d_in[8];
    const float* db1 = (const float*)d_in[9];
    const float* dw2 = (const float*)d_in[10];
    const float* db2 = (const float*)d_in[11];
    const float* dw3 = (const float*)d_in[12];
    const float* db3 = (const float*)d_in[13];
    float* out = (float*)d_out;

    const int B = in_sizes[0] / SD;
    const int ntiles = B / 16;                    // 262144 -> 16384

    // Single kernel: 1024 blocks x 4 waves = 4096 waves, 4 tiles (2 pairs)
    // per wave; 4 blocks/CU (LDS 28.7KB), no second launch, no d_ws.
    hipLaunchKernelGGL(qnet_kernel, dim3(1024), dim3(BLOCK), 0, stream,
                       state, ew1, eb1, ew2, eb2, ew3, eb3, qp,
                       dw1, db1, dw2, db2, dw3, db3, out, ntiles);
}

// Round 19
// 20.970 us; speedup vs baseline: 1.2369x; 1.1342x over previous
//
#include <hip/hip_runtime.h>
#include <math.h>

#define SD 39
#define BLOCK 1024   // 16 waves/block, ONE block per CU: prologue paid once
                     // per CU with 4x threads (was 4x blocks x 4x work).

typedef _Float16 half8 __attribute__((ext_vector_type(8)));
typedef float f32x4 __attribute__((ext_vector_type(4)));

// ---- LDS layout (dword offsets); per-lane MFMA fragments (see R14/R15).
// Frag arrays: [nfrag][64 lanes] of half8/f32x4 (16B each). Slot k-assignments
// are OUR choice, baked consistently into weight frags (prologue) and data
// frags (main loop); MFMA pairs A-slot(g,j) with B-slot(g,j).
#define DW_AW1 0      // 8 frags  (mt0..3 x ks0..1)   k = ks*32 + 8g + j ; 0 if k>=39
#define DW_AB1 2048   // 4 frags  f32x4 bias: eb1[mt*16+4g+r]
#define DW_AW2 3072   // 4 frags  (mt0..1 x ks0..1)   o1 = ks*32+16*(j>>2)+4g+(j&3)
#define DW_AB2 4096   // 2 frags  eb2[mt*16+4g+r]
#define DW_AW3 4608   // 1 frag   c<4: ew3[c][o2], o2=16*(j>>2)+4g+(j&3); else 0
#define DW_AB3 4864   // 1 frag   g==0 ? eb3[r] : 0
#define DW_AD1 5120   // 2 frags  (g==0&&j<4) ? dw1[(mt*16+c)*4+j] : 0
#define DW_AE1 5632   // 2 frags  db1[mt*16+4g+r]
#define DW_AD2 6144   // 1 frag   dw2[c*32 + 16*(j>>2)+4g+(j&3)]
#define DW_AE2 6400   // 1 frag   db2[4g+r]
#define DW_AD3 6656   // 1 frag   (c<8&&j<4) ? dw3[c*16+4g+j] : 0
#define DW_AE3 6912   // 1 frag   (4g+r<8) ? db3[4g+r] : 0
#define DW_QPE 7168   // qp[0,2,4,6]
#define DW_TOT 7172   // dwords = 28688 B LDS (one image per CU)

// Load one tile's state B-fragments (rows R..R+15, lane c owns row R+c).
#define LOAD_STATE(R, X0, X1)                                              \
    {                                                                      \
        const float* sp = state + ((R) + c) * SD;                          \
        float4 s0 = *(const float4*)(sp + 8 * g);                          \
        float4 s1 = *(const float4*)(sp + 8 * g + 4);                      \
        float4 s2 = make_float4(0.f, 0.f, 0.f, 0.f);                       \
        float4 s3 = make_float4(0.f, 0.f, 0.f, 0.f);                       \
        if (g == 0) {                                                      \
            s2 = *(const float4*)(sp + 32);                                \
            s3 = *(const float4*)(sp + 35);                                \
        }                                                                  \
        X0[0] = (_Float16)s0.x; X0[1] = (_Float16)s0.y;                    \
        X0[2] = (_Float16)s0.z; X0[3] = (_Float16)s0.w;                    \
        X0[4] = (_Float16)s1.x; X0[5] = (_Float16)s1.y;                    \
        X0[6] = (_Float16)s1.z; X0[7] = (_Float16)s1.w;                    \
        X1[0] = (_Float16)s2.x; X1[1] = (_Float16)s2.y;                    \
        X1[2] = (_Float16)s2.z; X1[3] = (_Float16)s2.w;                    \
        X1[4] = (_Float16)s3.y; X1[5] = (_Float16)s3.z;                    \
        X1[6] = (_Float16)s3.w; X1[7] = (_Float16)0.0f;                    \
    }

__global__ __launch_bounds__(BLOCK)
__attribute__((amdgpu_waves_per_eu(4)))   // 4 waves/SIMD -> VGPR<=128
void qnet_kernel(const float* __restrict__ state,
                 const float* __restrict__ ew1, const float* __restrict__ eb1,
                 const float* __restrict__ ew2, const float* __restrict__ eb2,
                 const float* __restrict__ ew3, const float* __restrict__ eb3,
                 const float* __restrict__ qp,
                 const float* __restrict__ dw1, const float* __restrict__ db1,
                 const float* __restrict__ dw2, const float* __restrict__ db2,
                 const float* __restrict__ dw3, const float* __restrict__ db3,
                 float* __restrict__ out, int ntiles)
{
    __shared__ __align__(16) float lf[DW_TOT];
    _Float16* wh = (_Float16*)lf;
    const int tid = threadIdx.x;

    // ---- fragment build (once per CU; <=5 iterations per thread) ----
    for (int i = tid; i < 8 * 512; i += BLOCK) {          // AW1
        int frag = i >> 9, lane = (i >> 3) & 63, j = i & 7;
        int mt = frag >> 1, ks = frag & 1, g = lane >> 4, c = lane & 15;
        int m = mt * 16 + c, k = ks * 32 + 8 * g + j;
        wh[DW_AW1 * 2 + i] = (k < SD) ? (_Float16)ew1[m * SD + k] : (_Float16)0.0f;
    }
    for (int i = tid; i < 4 * 512; i += BLOCK) {          // AW2
        int frag = i >> 9, lane = (i >> 3) & 63, j = i & 7;
        int mt = frag >> 1, ks = frag & 1, g = lane >> 4, c = lane & 15;
        int m = mt * 16 + c, o1 = ks * 32 + 16 * (j >> 2) + 4 * g + (j & 3);
        wh[DW_AW2 * 2 + i] = (_Float16)ew2[m * 64 + o1];
    }
    for (int i = tid; i < 512; i += BLOCK) {              // AW3
        int lane = (i >> 3) & 63, j = i & 7, g = lane >> 4, c = lane & 15;
        int o2 = 16 * (j >> 2) + 4 * g + (j & 3);
        wh[DW_AW3 * 2 + i] = (c < 4) ? (_Float16)ew3[c * 32 + o2] : (_Float16)0.0f;
    }
    for (int i = tid; i < 2 * 512; i += BLOCK) {          // AD1
        int frag = i >> 9, lane = (i >> 3) & 63, j = i & 7;
        int g = lane >> 4, c = lane & 15, m = frag * 16 + c;
        wh[DW_AD1 * 2 + i] = (g == 0 && j < 4) ? (_Float16)dw1[m * 4 + j]
                                               : (_Float16)0.0f;
    }
    for (int i = tid; i < 512; i += BLOCK) {              // AD2
        int lane = (i >> 3) & 63, j = i & 7, g = lane >> 4, c = lane & 15;
        int k1 = 16 * (j >> 2) + 4 * g + (j & 3);
        wh[DW_AD2 * 2 + i] = (_Float16)dw2[c * 32 + k1];
    }
    for (int i = tid; i < 512; i += BLOCK) {              // AD3
        int lane = (i >> 3) & 63, j = i & 7, g = lane >> 4, c = lane & 15;
        wh[DW_AD3 * 2 + i] = (c < 8 && j < 4) ? (_Float16)dw3[c * 16 + 4 * g + j]
                                              : (_Float16)0.0f;
    }
    for (int i = tid; i < 1024; i += BLOCK) {             // AB1
        int mt = i >> 8, lane = (i >> 2) & 63, r = i & 3, g = lane >> 4;
        lf[DW_AB1 + i] = eb1[mt * 16 + 4 * g + r];
    }
    for (int i = tid; i < 512; i += BLOCK) {              // AB2
        int mt = i >> 8, lane = (i >> 2) & 63, r = i & 3, g = lane >> 4;
        lf[DW_AB2 + i] = eb2[mt * 16 + 4 * g + r];
    }
    for (int i = tid; i < 256; i += BLOCK) {              // AB3
        int lane = (i >> 2) & 63, r = i & 3, g = lane >> 4;
        lf[DW_AB3 + i] = (g == 0) ? eb3[r] : 0.0f;
    }
    for (int i = tid; i < 512; i += BLOCK) {              // AE1
        int mt = i >> 8, lane = (i >> 2) & 63, r = i & 3, g = lane >> 4;
        lf[DW_AE1 + i] = db1[mt * 16 + 4 * g + r];
    }
    for (int i = tid; i < 256; i += BLOCK) {              // AE2
        int lane = (i >> 2) & 63, r = i & 3, g = lane >> 4;
        lf[DW_AE2 + i] = db2[4 * g + r];
    }
    for (int i = tid; i < 256; i += BLOCK) {              // AE3
        int lane = (i >> 2) & 63, r = i & 3, g = lane >> 4;
        lf[DW_AE3 + i] = (4 * g + r < 8) ? db3[4 * g + r] : 0.0f;
    }
    for (int i = tid; i < 4; i += BLOCK) lf[DW_QPE + i] = qp[2 * i];
    __syncthreads();

    const int lane = tid & 63;
    const int g = lane >> 4, c = lane & 15;
    const int gwave = blockIdx.x * (BLOCK / 64) + (tid >> 6);

    const half8* hws = (const half8*)lf;
    const f32x4* fws = (const f32x4*)lf;
    const float* qpep = lf + DW_QPE;

    // Paired tiles: each weight ds_read feeds both tiles' MFMAs; two
    // independent chains hide each other's latencies.
    for (int p = 2 * gwave; p < 2 * gwave + 2 && 2 * p + 1 < ntiles; p++) {
        const long long RA = (long long)(2 * p) * 16;
        const long long RB = RA + 16;

        half8 x0a, x1a, x0b, x1b;
        LOAD_STATE(RA, x0a, x1a)
        LOAD_STATE(RB, x0b, x1b)

        // ---- L1: 4 M-tiles x 2 K-steps ----
        f32x4 c1a[4], c1b[4];
        #pragma unroll
        for (int mt = 0; mt < 4; mt++) {
            half8 w0 = hws[DW_AW1 / 4 + (mt * 2 + 0) * 64 + lane];
            half8 w1 = hws[DW_AW1 / 4 + (mt * 2 + 1) * 64 + lane];
            f32x4 bias = fws[DW_AB1 / 4 + mt * 64 + lane];
            f32x4 ta = __builtin_amdgcn_mfma_f32_16x16x32_f16(w0, x0a, bias, 0, 0, 0);
            f32x4 tb = __builtin_amdgcn_mfma_f32_16x16x32_f16(w0, x0b, bias, 0, 0, 0);
            c1a[mt] = __builtin_amdgcn_mfma_f32_16x16x32_f16(w1, x1a, ta, 0, 0, 0);
            c1b[mt] = __builtin_amdgcn_mfma_f32_16x16x32_f16(w1, x1b, tb, 0, 0, 0);
        }
        half8 hb0a, hb1a, hb0b, hb1b;
        #pragma unroll
        for (int j = 0; j < 8; j++) {
            hb0a[j] = (_Float16)fmaxf(c1a[j >> 2][j & 3], 0.0f);
            hb1a[j] = (_Float16)fmaxf(c1a[2 + (j >> 2)][j & 3], 0.0f);
            hb0b[j] = (_Float16)fmaxf(c1b[j >> 2][j & 3], 0.0f);
            hb1b[j] = (_Float16)fmaxf(c1b[2 + (j >> 2)][j & 3], 0.0f);
        }

        // ---- L2: 2 M-tiles x 2 K-steps ----
        f32x4 c2a[2], c2b[2];
        #pragma unroll
        for (int mt = 0; mt < 2; mt++) {
            half8 w0 = hws[DW_AW2 / 4 + (mt * 2 + 0) * 64 + lane];
            half8 w1 = hws[DW_AW2 / 4 + (mt * 2 + 1) * 64 + lane];
            f32x4 bias = fws[DW_AB2 / 4 + mt * 64 + lane];
            f32x4 ta = __builtin_amdgcn_mfma_f32_16x16x32_f16(w0, hb0a, bias, 0, 0, 0);
            f32x4 tb = __builtin_amdgcn_mfma_f32_16x16x32_f16(w0, hb0b, bias, 0, 0, 0);
            c2a[mt] = __builtin_amdgcn_mfma_f32_16x16x32_f16(w1, hb1a, ta, 0, 0, 0);
            c2b[mt] = __builtin_amdgcn_mfma_f32_16x16x32_f16(w1, hb1b, tb, 0, 0, 0);
        }
        half8 hb2a, hb2b;
        #pragma unroll
        for (int j = 0; j < 8; j++) {
            hb2a[j] = (_Float16)fmaxf(c2a[j >> 2][j & 3], 0.0f);
            hb2b[j] = (_Float16)fmaxf(c2b[j >> 2][j & 3], 0.0f);
        }

        // ---- L3 ----
        half8 w3 = hws[DW_AW3 / 4 + lane];
        f32x4 b3 = fws[DW_AB3 / 4 + lane];
        f32x4 ea = __builtin_amdgcn_mfma_f32_16x16x32_f16(w3, hb2a, b3, 0, 0, 0);
        f32x4 eb = __builtin_amdgcn_mfma_f32_16x16x32_f16(w3, hb2b, b3, 0, 0, 0);

        // ---- quantum: ev_i = prod_{j<=i} cos(tanh(e_j)*pi + qp[2j]) ----
        // (RZ cancels under Z-measure; CNOT chain -> bit i = b0^..^bi)
        float eva[4], evb4[4]; float cpa = 1.0f, cpb = 1.0f;
        #pragma unroll
        for (int r = 0; r < 4; r++) {
            float exa = __expf(2.0f * ea[r]);
            float exb = __expf(2.0f * eb[r]);
            float ta = 1.0f - 2.0f / (exa + 1.0f);     // tanh(x)
            float tb = 1.0f - 2.0f / (exb + 1.0f);
            float qpe = qpep[r];
            cpa *= __cosf(fmaf(ta, 3.14159265358979323846f, qpe));
            cpb *= __cosf(fmaf(tb, 3.14159265358979323846f, qpe));
            eva[r] = cpa; evb4[r] = cpb;
        }
        half8 evfa, evfb;
        #pragma unroll
        for (int j = 0; j < 8; j++) {
            evfa[j] = (j < 4) ? (_Float16)eva[j] : (_Float16)0.0f;
            evfb[j] = (j < 4) ? (_Float16)evb4[j] : (_Float16)0.0f;
        }

        // ---- D1: 2 M-tiles ----
        f32x4 d1a[2], d1b[2];
        #pragma unroll
        for (int mt = 0; mt < 2; mt++) {
            half8 wd = hws[DW_AD1 / 4 + mt * 64 + lane];
            f32x4 be = fws[DW_AE1 / 4 + mt * 64 + lane];
            d1a[mt] = __builtin_amdgcn_mfma_f32_16x16x32_f16(wd, evfa, be, 0, 0, 0);
            d1b[mt] = __builtin_amdgcn_mfma_f32_16x16x32_f16(wd, evfb, be, 0, 0, 0);
        }
        half8 dba, dbb;
        #pragma unroll
        for (int j = 0; j < 8; j++) {
            dba[j] = (_Float16)fmaxf(d1a[j >> 2][j & 3], 0.0f);
            dbb[j] = (_Float16)fmaxf(d1b[j >> 2][j & 3], 0.0f);
        }

        // ---- D2 ----
        half8 wd2 = hws[DW_AD2 / 4 + lane];
        f32x4 be2 = fws[DW_AE2 / 4 + lane];
        f32x4 d2a = __builtin_amdgcn_mfma_f32_16x16x32_f16(wd2, dba, be2, 0, 0, 0);
        f32x4 d2b = __builtin_amdgcn_mfma_f32_16x16x32_f16(wd2, dbb, be2, 0, 0, 0);
        half8 d2fa, d2fb;
        #pragma unroll
        for (int j = 0; j < 8; j++) {
            d2fa[j] = (j < 4) ? (_Float16)fmaxf(d2a[j], 0.0f) : (_Float16)0.0f;
            d2fb[j] = (j < 4) ? (_Float16)fmaxf(d2b[j], 0.0f) : (_Float16)0.0f;
        }

        // ---- D3 + stores ----
        half8 wd3 = hws[DW_AD3 / 4 + lane];
        f32x4 be3 = fws[DW_AE3 / 4 + lane];
        f32x4 oa = __builtin_amdgcn_mfma_f32_16x16x32_f16(wd3, d2fa, be3, 0, 0, 0);
        f32x4 ob = __builtin_amdgcn_mfma_f32_16x16x32_f16(wd3, d2fb, be3, 0, 0, 0);

        if (lane < 32) {
            float4* opa = (float4*)(out + (RA + c) * 8 + 4 * g);
            *opa = make_float4(oa[0], oa[1], oa[2], oa[3]);
            float4* opb = (float4*)(out + (RB + c) * 8 + 4 * g);
            *opb = make_float4(ob[0], ob[1], ob[2], ob[3]);
        }
    }
}

extern "C" void kernel_launch(void* const* d_in, const int* in_sizes, int n_in,
                              void* d_out, int out_size, void* d_ws, size_t ws_size,
                              hipStream_t stream) {
    const float* state = (const float*)d_in[0];
    const float* ew1 = (const float*)d_in[1];
    const float* eb1 = (const float*)d_in[2];
    const float* ew2 = (const float*)d_in[3];
    const float* eb2 = (const float*)d_in[4];
    const float* ew3 = (const float*)d_in[5];
    const float* eb3 = (const float*)d_in[6];
    const float* qp  = (const float*)d_in[7];
    const float* dw1 = (const float*)d_in[8];
    const float* db1 = (const float*)d_in[9];
    const float* dw2 = (const float*)d_in[10];
    const float* db2 = (const float*)d_in[11];
    const float* dw3 = (const float*)d_in[12];
    const float* db3 = (const float*)d_in[13];
    float* out = (float*)d_out;

    const int B = in_sizes[0] / SD;
    const int ntiles = B / 16;                    // 262144 -> 16384

    // 256 blocks x 16 waves = 4096 waves, 4 tiles (2 pairs) per wave;
    // exactly 1 block/CU: prologue + LDS image once per CU.
    hipLaunchKernelGGL(qnet_kernel, dim3(256), dim3(BLOCK), 0, stream,
                       state, ew1, eb1, ew2, eb2, ew3, eb3, qp,
                       dw1, db1, dw2, db2, dw3, db3, out, ntiles);
}